// Round 3
// baseline (1703.981 us; speedup 1.0000x reference)
//
#include <hip/hip_runtime.h>

#define B_    8192
#define C_    256
#define L_    80
#define OUT_  64
#define HID_  128
#define FD_   128
#define NW_   15
#define NT_   122880
#define E_S_  262144
#define E_T_  983040

// ---------------------------------------------------------------------------
// K1: one streaming pass over x: node_x[b,c] = mean_L, red[b*15+w, c] = window mean
// ---------------------------------------------------------------------------
__global__ __launch_bounds__(256) void k_reduce_x(const float* __restrict__ x,
                                                  float* __restrict__ node_x,
                                                  float* __restrict__ red) {
    int gid = blockIdx.x * 256 + threadIdx.x;          // = b*C + c
    const float4* row4 = reinterpret_cast<const float4*>(x + (size_t)gid * L_);
    float v[L_];
#pragma unroll
    for (int i = 0; i < L_ / 4; ++i) {
        float4 t = row4[i];
        v[4*i+0] = t.x; v[4*i+1] = t.y; v[4*i+2] = t.z; v[4*i+3] = t.w;
    }
    float s5[16];
    float tot = 0.f;
#pragma unroll
    for (int j = 0; j < 16; ++j) {
        float s = 0.f;
#pragma unroll
        for (int k = 0; k < 5; ++k) s += v[5*j + k];
        s5[j] = s; tot += s;
    }
    node_x[gid] = tot * (1.f / L_);
    int b = gid >> 8;
    int c = gid & 255;
#pragma unroll
    for (int w = 0; w < NW_; ++w)
        red[((size_t)(b * NW_ + w)) * C_ + c] = (s5[w] + s5[w + 1]) * 0.1f;
}

// ---------------------------------------------------------------------------
// fp32 GEMM: C[N,M] = A[N,K] @ W[K,M] (+bias) (optional relu)
// BM=BN=64, BK=16, 256 threads, 4x4 microtile.
// ---------------------------------------------------------------------------
#define BM 64
#define BN 64
#define BK 16
__global__ __launch_bounds__(256) void k_gemm(const float* __restrict__ A,
                                              const float* __restrict__ W,
                                              const float* __restrict__ bias,
                                              float* __restrict__ Co,
                                              int N, int K, int M, int relu) {
    __shared__ float As[BK][BM];
    __shared__ float Ws[BK][BN];
    int t = threadIdx.x;
    int row0 = blockIdx.x * BM;
    int col0 = blockIdx.y * BN;
    int lr = t >> 2;
    int lk = (t & 3) * 4;
    int wk = t >> 4;
    int wc = (t & 15) * 4;
    int ty = t >> 4;
    int tx = t & 15;
    float acc[4][4] = {};
    for (int k0 = 0; k0 < K; k0 += BK) {
        float4 av = *reinterpret_cast<const float4*>(&A[(size_t)(row0 + lr) * K + k0 + lk]);
        float4 wv = *reinterpret_cast<const float4*>(&W[(size_t)(k0 + wk) * M + col0 + wc]);
        __syncthreads();
        As[lk + 0][lr] = av.x; As[lk + 1][lr] = av.y;
        As[lk + 2][lr] = av.z; As[lk + 3][lr] = av.w;
        *reinterpret_cast<float4*>(&Ws[wk][wc]) = wv;
        __syncthreads();
#pragma unroll
        for (int kk = 0; kk < BK; ++kk) {
            float4 a  = *reinterpret_cast<const float4*>(&As[kk][ty * 4]);
            float4 w4 = *reinterpret_cast<const float4*>(&Ws[kk][tx * 4]);
            acc[0][0] += a.x * w4.x; acc[0][1] += a.x * w4.y; acc[0][2] += a.x * w4.z; acc[0][3] += a.x * w4.w;
            acc[1][0] += a.y * w4.x; acc[1][1] += a.y * w4.y; acc[1][2] += a.y * w4.z; acc[1][3] += a.y * w4.w;
            acc[2][0] += a.z * w4.x; acc[2][1] += a.z * w4.y; acc[2][2] += a.z * w4.z; acc[2][3] += a.z * w4.w;
            acc[3][0] += a.w * w4.x; acc[3][1] += a.w * w4.y; acc[3][2] += a.w * w4.z; acc[3][3] += a.w * w4.w;
        }
    }
    int cbase = col0 + tx * 4;
    float4 bv = make_float4(0.f, 0.f, 0.f, 0.f);
    if (bias) bv = *reinterpret_cast<const float4*>(&bias[cbase]);
#pragma unroll
    for (int i = 0; i < 4; ++i) {
        int r = row0 + ty * 4 + i;
        float4 o;
        o.x = acc[i][0] + bv.x; o.y = acc[i][1] + bv.y;
        o.z = acc[i][2] + bv.z; o.w = acc[i][3] + bv.w;
        if (relu) {
            o.x = fmaxf(o.x, 0.f); o.y = fmaxf(o.y, 0.f);
            o.z = fmaxf(o.z, 0.f); o.w = fmaxf(o.w, 0.f);
        }
        *reinterpret_cast<float4*>(&Co[(size_t)r * M + cbase]) = o;
    }
}

// ---------------------------------------------------------------------------
// Dual GEMM sharing the A tile: C1 = A@W1 (no bias), C2 = A@W2 + b2.
// ---------------------------------------------------------------------------
__global__ __launch_bounds__(256) void k_gemm_dual(const float* __restrict__ A,
                                                   const float* __restrict__ W1,
                                                   float* __restrict__ C1,
                                                   const float* __restrict__ W2,
                                                   const float* __restrict__ b2,
                                                   float* __restrict__ C2,
                                                   int N, int K, int M) {
    __shared__ float As[BK][BM];
    __shared__ float W1s[BK][BN];
    __shared__ float W2s[BK][BN];
    int t = threadIdx.x;
    int row0 = blockIdx.x * BM;
    int col0 = blockIdx.y * BN;
    int lr = t >> 2;
    int lk = (t & 3) * 4;
    int wk = t >> 4;
    int wc = (t & 15) * 4;
    int ty = t >> 4;
    int tx = t & 15;
    float acc1[4][4] = {};
    float acc2[4][4] = {};
    for (int k0 = 0; k0 < K; k0 += BK) {
        float4 av  = *reinterpret_cast<const float4*>(&A[(size_t)(row0 + lr) * K + k0 + lk]);
        float4 w1v = *reinterpret_cast<const float4*>(&W1[(size_t)(k0 + wk) * M + col0 + wc]);
        float4 w2v = *reinterpret_cast<const float4*>(&W2[(size_t)(k0 + wk) * M + col0 + wc]);
        __syncthreads();
        As[lk + 0][lr] = av.x; As[lk + 1][lr] = av.y;
        As[lk + 2][lr] = av.z; As[lk + 3][lr] = av.w;
        *reinterpret_cast<float4*>(&W1s[wk][wc]) = w1v;
        *reinterpret_cast<float4*>(&W2s[wk][wc]) = w2v;
        __syncthreads();
#pragma unroll
        for (int kk = 0; kk < BK; ++kk) {
            float4 a  = *reinterpret_cast<const float4*>(&As[kk][ty * 4]);
            float4 u  = *reinterpret_cast<const float4*>(&W1s[kk][tx * 4]);
            float4 w  = *reinterpret_cast<const float4*>(&W2s[kk][tx * 4]);
            acc1[0][0] += a.x * u.x; acc1[0][1] += a.x * u.y; acc1[0][2] += a.x * u.z; acc1[0][3] += a.x * u.w;
            acc1[1][0] += a.y * u.x; acc1[1][1] += a.y * u.y; acc1[1][2] += a.y * u.z; acc1[1][3] += a.y * u.w;
            acc1[2][0] += a.z * u.x; acc1[2][1] += a.z * u.y; acc1[2][2] += a.z * u.z; acc1[2][3] += a.z * u.w;
            acc1[3][0] += a.w * u.x; acc1[3][1] += a.w * u.y; acc1[3][2] += a.w * u.z; acc1[3][3] += a.w * u.w;
            acc2[0][0] += a.x * w.x; acc2[0][1] += a.x * w.y; acc2[0][2] += a.x * w.z; acc2[0][3] += a.x * w.w;
            acc2[1][0] += a.y * w.x; acc2[1][1] += a.y * w.y; acc2[1][2] += a.y * w.z; acc2[1][3] += a.y * w.w;
            acc2[2][0] += a.z * w.x; acc2[2][1] += a.z * w.y; acc2[2][2] += a.z * w.z; acc2[2][3] += a.z * w.w;
            acc2[3][0] += a.w * w.x; acc2[3][1] += a.w * w.y; acc2[3][2] += a.w * w.z; acc2[3][3] += a.w * w.w;
        }
    }
    int cbase = col0 + tx * 4;
    float4 bv = *reinterpret_cast<const float4*>(&b2[cbase]);
#pragma unroll
    for (int i = 0; i < 4; ++i) {
        int r = row0 + ty * 4 + i;
        float4 o1, o2;
        o1.x = acc1[i][0]; o1.y = acc1[i][1]; o1.z = acc1[i][2]; o1.w = acc1[i][3];
        o2.x = acc2[i][0] + bv.x; o2.y = acc2[i][1] + bv.y;
        o2.z = acc2[i][2] + bv.z; o2.w = acc2[i][3] + bv.w;
        *reinterpret_cast<float4*>(&C1[(size_t)r * M + cbase]) = o1;
        *reinterpret_cast<float4*>(&C2[(size_t)r * M + cbase]) = o2;
    }
}

// ---------------------------------------------------------------------------
// CSR build: int histogram -> block scan -> serial top scan -> add-back -> scatter
// ---------------------------------------------------------------------------
__global__ __launch_bounds__(256) void k_cnt(const int* __restrict__ dst,
                                             int* __restrict__ cnt, int E) {
    int g = blockIdx.x * 256 + threadIdx.x;
    if (g < E) atomicAdd(&cnt[dst[g]], 1);
}

// exclusive scan within each 256-block; rs <- excl-in-block, bsum[blk] <- block total
__global__ __launch_bounds__(256) void k_scan_blk(const int* __restrict__ cnt,
                                                  int* __restrict__ rs,
                                                  int* __restrict__ bsum, int N) {
    __shared__ int s[256];
    int g = blockIdx.x * 256 + threadIdx.x;
    int v = (g < N) ? cnt[g] : 0;
    s[threadIdx.x] = v;
    __syncthreads();
    for (int off = 1; off < 256; off <<= 1) {
        int t = (threadIdx.x >= off) ? s[threadIdx.x - off] : 0;
        __syncthreads();
        s[threadIdx.x] += t;
        __syncthreads();
    }
    if (g < N) rs[g] = s[threadIdx.x] - v;
    if (threadIdx.x == 255) bsum[blockIdx.x] = s[255];
}

__global__ void k_scan_top(int* __restrict__ bsum, int nb) {
    if (threadIdx.x == 0 && blockIdx.x == 0) {
        int acc = 0;
        for (int i = 0; i < nb; ++i) { int v = bsum[i]; bsum[i] = acc; acc += v; }
    }
}

__global__ __launch_bounds__(256) void k_scan_add(int* __restrict__ rs,
                                                  const int* __restrict__ bsum,
                                                  int* __restrict__ fill, int N) {
    int g = blockIdx.x * 256 + threadIdx.x;
    if (g < N) {
        int v = rs[g] + bsum[blockIdx.x];
        rs[g] = v;
        fill[g] = v;
    }
}

__global__ __launch_bounds__(256) void k_scatter(const int* __restrict__ src,
                                                 const int* __restrict__ dst,
                                                 int* __restrict__ fill,
                                                 int* __restrict__ csr, int E) {
    int g = blockIdx.x * 256 + threadIdx.x;
    if (g < E) {
        int p = atomicAdd(&fill[dst[g]], 1);
        csr[p] = src[g];
    }
}

// ---------------------------------------------------------------------------
// CSR aggregation, H=128, fused epilogue: Hout = relu(mean_agg(Y) + Z)
// one wave per dst row; 64 lanes x float2 = coalesced 512B row reads
// ---------------------------------------------------------------------------
__global__ __launch_bounds__(256) void k_agg128(const int* __restrict__ rs,
                                                const int* __restrict__ cnt,
                                                const int* __restrict__ csr,
                                                const float* __restrict__ Y,
                                                const float* __restrict__ Z,
                                                float* __restrict__ Hout, int N) {
    int wid = (blockIdx.x * 256 + threadIdx.x) >> 6;
    int lane = threadIdx.x & 63;
    if (wid >= N) return;
    int s0 = rs[wid], c = cnt[wid];
    float2 acc = make_float2(0.f, 0.f);
    int j = 0;
    for (; j + 1 < c; j += 2) {
        int sa = csr[s0 + j], sb = csr[s0 + j + 1];
        float2 va = *reinterpret_cast<const float2*>(&Y[(size_t)sa * 128 + lane * 2]);
        float2 vb = *reinterpret_cast<const float2*>(&Y[(size_t)sb * 128 + lane * 2]);
        acc.x += va.x + vb.x; acc.y += va.y + vb.y;
    }
    if (j < c) {
        int sa = csr[s0 + j];
        float2 va = *reinterpret_cast<const float2*>(&Y[(size_t)sa * 128 + lane * 2]);
        acc.x += va.x; acc.y += va.y;
    }
    float rc = 1.f / fmaxf((float)c, 1.f);
    size_t idx = (size_t)wid * 128 + lane * 2;
    float2 z = *reinterpret_cast<const float2*>(&Z[idx]);
    float2 o;
    o.x = fmaxf(acc.x * rc + z.x, 0.f);
    o.y = fmaxf(acc.y * rc + z.y, 0.f);
    *reinterpret_cast<float2*>(&Hout[idx]) = o;
}

// ---------------------------------------------------------------------------
// CSR aggregation, H=64, fused epilogue: emb = l2norm(mean_agg(Y) + Z)
// ---------------------------------------------------------------------------
__global__ __launch_bounds__(256) void k_agg64n(const int* __restrict__ rs,
                                                const int* __restrict__ cnt,
                                                const int* __restrict__ csr,
                                                const float* __restrict__ Y,
                                                const float* __restrict__ Z,
                                                float* __restrict__ emb, int N) {
    int wid = (blockIdx.x * 256 + threadIdx.x) >> 6;
    int lane = threadIdx.x & 63;
    if (wid >= N) return;
    int s0 = rs[wid], c = cnt[wid];
    float acc = 0.f;
    int j = 0;
    for (; j + 1 < c; j += 2) {
        int sa = csr[s0 + j], sb = csr[s0 + j + 1];
        acc += Y[(size_t)sa * 64 + lane] + Y[(size_t)sb * 64 + lane];
    }
    if (j < c) acc += Y[(size_t)csr[s0 + j] * 64 + lane];
    float rc = 1.f / fmaxf((float)c, 1.f);
    size_t idx = (size_t)wid * 64 + lane;
    float v = acc * rc + Z[idx];
    float ss = v * v;
#pragma unroll
    for (int m = 32; m; m >>= 1) ss += __shfl_xor(ss, m, 64);
    float inv = 1.f / fmaxf(sqrtf(ss), 1e-12f);
    emb[idx] = v * inv;
}

// ---------------------------------------------------------------------------
// row L2-norm, dim 128: one wave per row
// ---------------------------------------------------------------------------
__global__ __launch_bounds__(256) void k_l2n128(const float* __restrict__ in,
                                                float* __restrict__ out, int N) {
    int wid = (blockIdx.x * 256 + threadIdx.x) >> 6;
    int lane = threadIdx.x & 63;
    if (wid >= N) return;
    size_t idx = (size_t)wid * 128 + lane * 2;
    float2 v = *reinterpret_cast<const float2*>(&in[idx]);
    float ss = v.x * v.x + v.y * v.y;
#pragma unroll
    for (int m = 32; m; m >>= 1) ss += __shfl_xor(ss, m, 64);
    float inv = 1.f / fmaxf(sqrtf(ss), 1e-12f);
    float2 o; o.x = v.x * inv; o.y = v.y * inv;
    *reinterpret_cast<float2*>(&out[idx]) = o;
}

// ---------------------------------------------------------------------------
// temporal window-mean: out[b,o] = mean_w emb[(b*15+w)*64 + o]
// ---------------------------------------------------------------------------
__global__ __launch_bounds__(256) void k_tmean(const float* __restrict__ emb,
                                               float* __restrict__ out) {
    int gid = blockIdx.x * 256 + threadIdx.x;
    if (gid >= B_ * OUT_) return;
    int b = gid >> 6;
    int o = gid & 63;
    float s = 0.f;
#pragma unroll
    for (int w = 0; w < NW_; ++w) s += emb[((size_t)(b * NW_ + w)) * OUT_ + o];
    out[gid] = s * (1.f / NW_);
}

// ---------------------------------------------------------------------------
extern "C" void kernel_launch(void* const* d_in, const int* in_sizes, int n_in,
                              void* d_out, int out_size, void* d_ws, size_t ws_size,
                              hipStream_t stream) {
    const float* x      = (const float*)d_in[0];
    const int*   s_ei   = (const int*)d_in[1];
    const int*   t_ei   = (const int*)d_in[2];
    const float* s_l1_W  = (const float*)d_in[3];
    const float* s_l1_b  = (const float*)d_in[4];
    const float* s_l1_Wr = (const float*)d_in[5];
    const float* s_l2_W  = (const float*)d_in[6];
    const float* s_l2_b  = (const float*)d_in[7];
    const float* s_l2_Wr = (const float*)d_in[8];
    const float* s_p1_W  = (const float*)d_in[9];
    const float* s_p1_b  = (const float*)d_in[10];
    const float* s_p2_W  = (const float*)d_in[11];
    const float* s_p2_b  = (const float*)d_in[12];
    const float* t_l1_W  = (const float*)d_in[13];
    const float* t_l1_b  = (const float*)d_in[14];
    const float* t_l1_Wr = (const float*)d_in[15];
    const float* t_l2_W  = (const float*)d_in[16];
    const float* t_l2_b  = (const float*)d_in[17];
    const float* t_l2_Wr = (const float*)d_in[18];
    const float* t_p1_W  = (const float*)d_in[19];
    const float* t_p1_b  = (const float*)d_in[20];
    const float* t_p2_W  = (const float*)d_in[21];
    const float* t_p2_b  = (const float*)d_in[22];

    const int* s_src = s_ei, *s_dst = s_ei + E_S_;
    const int* t_src = t_ei, *t_dst = t_ei + E_T_;

    float* ws   = (float*)d_ws;
    float* dout = (float*)d_out;

    // ---- workspace layout (4B elements), lifetime-aliased; peak 64,684,544 el = 259 MB ----
    // phase A (K1 + spatial): red | nodex | sY..sT | s_csr ints
    // phase B (t lin1):       red | tY (over nodex+spatial scratch) | tZ | t ints
    // phase C (t agg/l2):     tH t2Y t2Z (over red) | tE (over tY) | tM/tP/tT (over tY tail)
    float* red    = ws + 0;          // 31457280 = NT*C
    float* nodex  = ws + 31457280;   // 2097152
    float* sY     = ws + 33554432;   // 1048576
    float* sZ     = ws + 34603008;   // 1048576
    float* sH     = ws + 35651584;   // 1048576
    float* s2Y    = ws + 36700160;   // 524288
    float* s2Z    = ws + 37224448;   // 524288
    float* sE     = ws + 37748736;   // 524288
    float* sP     = ws + 38273024;   // 1048576
    float* sT     = ws + 39321600;   // 1048576
    // temporal big buffers
    float* tY     = ws + 31457280;   // 15728640 (over nodex+spatial, dead by t-lin1)
    float* tZ     = ws + 47185920;   // 15728640
    float* tH     = ws + 0;          // 15728640 (over red, dead after t-lin1)
    float* t2Y    = ws + 15728640;   // 7864320  (over red)
    float* t2Z    = ws + 23592960;   // 7864320  (over red)
    float* tE     = ws + 31457280;   // 7864320  (over tY, dead after t-agg1)
    float* tM     = ws + 39321600;   // 524288   (over old tY tail / sT region, dead)
    float* tP     = ws + 39845888;   // 1048576
    float* tT     = ws + 40894464;   // 1048576
    // int scratch (beyond tZ)
    int* s_cnt  = (int*)(ws + 62914560);   // 8192
    int* s_rs   = (int*)(ws + 62922752);   // 8192
    int* s_fill = (int*)(ws + 62930944);   // 8192
    int* s_csr  = (int*)(ws + 62939136);   // 262144
    int* t_cnt  = (int*)(ws + 63201280);   // 122880
    int* t_rs   = (int*)(ws + 63324160);   // 122880
    int* t_fill = (int*)(ws + 63447040);   // 122880
    int* t_csr  = (int*)(ws + 63569920);   // 983040
    int* bsum   = (int*)(ws + 64552960);   // 512     -> peak end 64553472 (<64684544)

    // ---- K1: x -> node_x, red ----
    k_reduce_x<<<(B_ * C_) / 256, 256, 0, stream>>>(x, nodex, red);

    // ================= spatial CSR build (shared by both spatial layers) ==========
    hipMemsetAsync(s_cnt, 0, (size_t)B_ * 4, stream);
    k_cnt<<<E_S_ / 256, 256, 0, stream>>>(s_dst, s_cnt, E_S_);
    k_scan_blk<<<B_ / 256, 256, 0, stream>>>(s_cnt, s_rs, bsum, B_);
    k_scan_top<<<1, 1, 0, stream>>>(bsum, B_ / 256);
    k_scan_add<<<B_ / 256, 256, 0, stream>>>(s_rs, bsum, s_fill, B_);
    k_scatter<<<E_S_ / 256, 256, 0, stream>>>(s_src, s_dst, s_fill, s_csr, E_S_);

    // ================= spatial encoder (N = 8192) =================
    k_gemm_dual<<<dim3(B_ / 64, HID_ / 64), 256, 0, stream>>>(nodex, s_l1_W, sY, s_l1_Wr, s_l1_b, sZ, B_, C_, HID_);
    k_agg128<<<B_ / 4, 256, 0, stream>>>(s_rs, s_cnt, s_csr, sY, sZ, sH, B_);
    k_gemm_dual<<<dim3(B_ / 64, OUT_ / 64), 256, 0, stream>>>(sH, s_l2_W, s2Y, s_l2_Wr, s_l2_b, s2Z, B_, HID_, OUT_);
    k_agg64n<<<B_ / 4, 256, 0, stream>>>(s_rs, s_cnt, s_csr, s2Y, s2Z, sE, B_);
    k_gemm<<<dim3(B_ / 64, FD_ / 64), 256, 0, stream>>>(sE, s_p1_W, s_p1_b, sP, B_, OUT_, FD_, 1);
    k_gemm<<<dim3(B_ / 64, FD_ / 64), 256, 0, stream>>>(sP, s_p2_W, s_p2_b, sT, B_, FD_, FD_, 0);
    k_l2n128<<<B_ / 4, 256, 0, stream>>>(sT, dout, B_);

    // ================= temporal CSR build =================
    hipMemsetAsync(t_cnt, 0, (size_t)NT_ * 4, stream);
    k_cnt<<<E_T_ / 256, 256, 0, stream>>>(t_dst, t_cnt, E_T_);
    k_scan_blk<<<NT_ / 256, 256, 0, stream>>>(t_cnt, t_rs, bsum, NT_);
    k_scan_top<<<1, 1, 0, stream>>>(bsum, NT_ / 256);
    k_scan_add<<<NT_ / 256, 256, 0, stream>>>(t_rs, bsum, t_fill, NT_);
    k_scatter<<<E_T_ / 256, 256, 0, stream>>>(t_src, t_dst, t_fill, t_csr, E_T_);

    // ================= temporal encoder (N = 122880) =================
    k_gemm_dual<<<dim3(NT_ / 64, HID_ / 64), 256, 0, stream>>>(red, t_l1_W, tY, t_l1_Wr, t_l1_b, tZ, NT_, C_, HID_);
    // red dead from here
    k_agg128<<<NT_ / 4, 256, 0, stream>>>(t_rs, t_cnt, t_csr, tY, tZ, tH, NT_);
    k_gemm_dual<<<dim3(NT_ / 64, OUT_ / 64), 256, 0, stream>>>(tH, t_l2_W, t2Y, t_l2_Wr, t_l2_b, t2Z, NT_, HID_, OUT_);
    k_agg64n<<<NT_ / 4, 256, 0, stream>>>(t_rs, t_cnt, t_csr, t2Y, t2Z, tE, NT_);
    k_tmean<<<(B_ * OUT_) / 256, 256, 0, stream>>>(tE, tM);
    k_gemm<<<dim3(B_ / 64, FD_ / 64), 256, 0, stream>>>(tM, t_p1_W, t_p1_b, tP, B_, OUT_, FD_, 1);
    k_gemm<<<dim3(B_ / 64, FD_ / 64), 256, 0, stream>>>(tP, t_p2_W, t_p2_b, tT, B_, FD_, FD_, 0);
    k_l2n128<<<B_ / 4, 256, 0, stream>>>(tT, dout + (size_t)B_ * FD_, B_);
}

// Round 8
// 1519.161 us; speedup vs baseline: 1.1217x; 1.1217x over previous
//
#include <hip/hip_runtime.h>

#define B_    8192
#define C_    256
#define L_    80
#define OUT_  64
#define HID_  128
#define FD_   128
#define NW_   15
#define NT_   122880
#define E_S_  262144
#define E_T_  983040

typedef unsigned short ushort_t;
typedef __attribute__((ext_vector_type(8))) short bf16x8;
typedef __attribute__((ext_vector_type(4))) float f32x4;

// round-to-nearest-even bf16 split: a ~= hi + lo (17-bit effective mantissa)
__device__ inline void split_bf16(float a, ushort_t& h, ushort_t& l) {
    unsigned u = __float_as_uint(a);
    unsigned hb = (u + 0x7FFFu + ((u >> 16) & 1u)) & 0xFFFF0000u;
    h = (ushort_t)(hb >> 16);
    float r = a - __uint_as_float(hb);
    unsigned v = __float_as_uint(r);
    l = (ushort_t)((v + 0x7FFFu + ((v >> 16) & 1u)) >> 16);
}

// ---------------------------------------------------------------------------
// K1: one pass over x -> node_x (bf16 hi/lo) and red (bf16 hi/lo)
// ---------------------------------------------------------------------------
__global__ __launch_bounds__(256) void k_reduce_x(const float* __restrict__ x,
                                                  ushort_t* __restrict__ node_h,
                                                  ushort_t* __restrict__ node_l,
                                                  ushort_t* __restrict__ red_h,
                                                  ushort_t* __restrict__ red_l) {
    int gid = blockIdx.x * 256 + threadIdx.x;          // = b*C + c
    const float4* row4 = reinterpret_cast<const float4*>(x + (size_t)gid * L_);
    float v[L_];
#pragma unroll
    for (int i = 0; i < L_ / 4; ++i) {
        float4 t = row4[i];
        v[4*i+0] = t.x; v[4*i+1] = t.y; v[4*i+2] = t.z; v[4*i+3] = t.w;
    }
    float s5[16];
    float tot = 0.f;
#pragma unroll
    for (int j = 0; j < 16; ++j) {
        float s = 0.f;
#pragma unroll
        for (int k = 0; k < 5; ++k) s += v[5*j + k];
        s5[j] = s; tot += s;
    }
    ushort_t h, l;
    split_bf16(tot * (1.f / L_), h, l);
    node_h[gid] = h; node_l[gid] = l;
    int b = gid >> 8;
    int c = gid & 255;
#pragma unroll
    for (int w = 0; w < NW_; ++w) {
        split_bf16((s5[w] + s5[w + 1]) * 0.1f, h, l);
        size_t idx = ((size_t)(b * NW_ + w)) * C_ + c;
        red_h[idx] = h; red_l[idx] = l;
    }
}

// ---------------------------------------------------------------------------
// merged weight conversion: 8 fp32 W[K][M] -> transposed bf16 hi/lo in one blob
// segments: s_l1, s_r1, s_l2, s_r2, t_l1, t_r1, t_l2, t_r2
// ---------------------------------------------------------------------------
__global__ __launch_bounds__(256) void k_conv_all(
        const float* __restrict__ w0, const float* __restrict__ w1,
        const float* __restrict__ w2, const float* __restrict__ w3,
        const float* __restrict__ w4, const float* __restrict__ w5,
        const float* __restrict__ w6, const float* __restrict__ w7,
        ushort_t* __restrict__ blob) {
    const int bstart[9] = {0, 128, 256, 288, 320, 448, 576, 608, 640};
    const int Ks[8]     = {256, 256, 128, 128, 256, 256, 128, 128};
    const int hoff[8]   = {0, 65536, 131072, 147456, 163840, 229376, 294912, 311296};
    int blk = blockIdx.x;
    int seg = 0;
    while (blk >= bstart[seg + 1]) ++seg;
    const float* W = (seg == 0) ? w0 : (seg == 1) ? w1 : (seg == 2) ? w2 : (seg == 3) ? w3
                   : (seg == 4) ? w4 : (seg == 5) ? w5 : (seg == 6) ? w6 : w7;
    int K = Ks[seg];
    int nel = (bstart[seg + 1] - bstart[seg]) * 256;
    int M = nel / K;
    int g = (blk - bstart[seg]) * 256 + threadIdx.x;
    int k = g / M, m = g - k * M;
    ushort_t h, l;
    split_bf16(W[g], h, l);
    blob[hoff[seg] + m * K + k] = h;
    blob[hoff[seg] + nel + m * K + k] = l;
}

// ---------------------------------------------------------------------------
// split-bf16 MFMA GEMM: C[N][BN] = (Ah+Al)[N][KTOT] @ (Wh+Wl)^T  (+bias)
// BM=128 rows/block, BN=NF*32 cols (full M of one weight), 256 thr = 4 waves 2x2.
// LDS rows padded to 72 shorts (144 B = 9*16B): 16B-aligned frag reads, 2-way banks (free).
// 3 MFMA per frag-pair: hi*hi + hi*lo + lo*hi  (lo*lo ~ 2^-18, dropped)
// ---------------------------------------------------------------------------
template<int KTOT, int NF>
__global__ __launch_bounds__(256, 2) void k_mfma_gemm(const ushort_t* __restrict__ Ah,
                                                      const ushort_t* __restrict__ Al,
                                                      const ushort_t* __restrict__ Wh,
                                                      const ushort_t* __restrict__ Wl,
                                                      const float* __restrict__ bias,
                                                      float* __restrict__ C) {
    constexpr int BN = NF * 32;
    __shared__ short sAh[128][72], sAl[128][72], sWh[128][72], sWl[128][72];
    int t = threadIdx.x;
    int row0 = blockIdx.x * 128;
    int wid = t >> 6, lane = t & 63;
    int wr = wid >> 1, wc = wid & 1;
    int lrow = lane & 15, lkg = lane >> 4;

    f32x4 acc[4][NF];
#pragma unroll
    for (int mi = 0; mi < 4; ++mi)
#pragma unroll
        for (int ni = 0; ni < NF; ++ni) {
            acc[mi][ni].x = 0.f; acc[mi][ni].y = 0.f;
            acc[mi][ni].z = 0.f; acc[mi][ni].w = 0.f;
        }

    for (int k0 = 0; k0 < KTOT; k0 += 64) {
        __syncthreads();
        // stage A tile: 128 rows x 64 k, hi+lo. 1024 chunks of 16B per buffer.
#pragma unroll
        for (int i = 0; i < 4; ++i) {
            int ch = t + i * 256;
            int r = ch >> 3, c = ch & 7;
            *reinterpret_cast<int4*>(&sAh[r][c * 8]) =
                *reinterpret_cast<const int4*>(&Ah[(size_t)(row0 + r) * KTOT + k0 + c * 8]);
            *reinterpret_cast<int4*>(&sAl[r][c * 8]) =
                *reinterpret_cast<const int4*>(&Al[(size_t)(row0 + r) * KTOT + k0 + c * 8]);
        }
        // stage W tile: BN rows x 64 k, hi+lo
#pragma unroll
        for (int i = 0; i < 4; ++i) {
            int ch = t + i * 256;
            int r = ch >> 3, c = ch & 7;
            if (r < BN) {
                *reinterpret_cast<int4*>(&sWh[r][c * 8]) =
                    *reinterpret_cast<const int4*>(&Wh[(size_t)r * KTOT + k0 + c * 8]);
                *reinterpret_cast<int4*>(&sWl[r][c * 8]) =
                    *reinterpret_cast<const int4*>(&Wl[(size_t)r * KTOT + k0 + c * 8]);
            }
        }
        __syncthreads();
#pragma unroll
        for (int ks = 0; ks < 64; ks += 32) {
            bf16x8 ah[4], al[4], wh[NF], wl[NF];
            int kk = ks + lkg * 8;
#pragma unroll
            for (int mi = 0; mi < 4; ++mi) {
                int r = wr * 64 + mi * 16 + lrow;
                ah[mi] = *reinterpret_cast<const bf16x8*>(&sAh[r][kk]);
                al[mi] = *reinterpret_cast<const bf16x8*>(&sAl[r][kk]);
            }
#pragma unroll
            for (int ni = 0; ni < NF; ++ni) {
                int r = wc * (NF * 16) + ni * 16 + lrow;
                wh[ni] = *reinterpret_cast<const bf16x8*>(&sWh[r][kk]);
                wl[ni] = *reinterpret_cast<const bf16x8*>(&sWl[r][kk]);
            }
#pragma unroll
            for (int mi = 0; mi < 4; ++mi)
#pragma unroll
                for (int ni = 0; ni < NF; ++ni) {
                    acc[mi][ni] = __builtin_amdgcn_mfma_f32_16x16x32_bf16(ah[mi], wh[ni], acc[mi][ni], 0, 0, 0);
                    acc[mi][ni] = __builtin_amdgcn_mfma_f32_16x16x32_bf16(ah[mi], wl[ni], acc[mi][ni], 0, 0, 0);
                    acc[mi][ni] = __builtin_amdgcn_mfma_f32_16x16x32_bf16(al[mi], wh[ni], acc[mi][ni], 0, 0, 0);
                }
        }
    }
    // epilogue: C/D mapping col=lane&15, row=(lane>>4)*4+reg
    float bv[NF];
#pragma unroll
    for (int ni = 0; ni < NF; ++ni) {
        int gcol = wc * (NF * 16) + ni * 16 + lrow;
        bv[ni] = bias ? bias[gcol] : 0.f;
    }
#pragma unroll
    for (int mi = 0; mi < 4; ++mi)
#pragma unroll
        for (int ni = 0; ni < NF; ++ni) {
            int gcol = wc * (NF * 16) + ni * 16 + lrow;
#pragma unroll
            for (int j = 0; j < 4; ++j) {
                int grow = row0 + wr * 64 + mi * 16 + lkg * 4 + j;
                C[(size_t)grow * BN + gcol] = acc[mi][ni][j] + bv[ni];
            }
        }
}

// ---------------------------------------------------------------------------
// CSR build
// ---------------------------------------------------------------------------
__global__ __launch_bounds__(256) void k_cnt(const int* __restrict__ dst,
                                             int* __restrict__ cnt, int E) {
    int g = blockIdx.x * 256 + threadIdx.x;
    if (g < E) atomicAdd(&cnt[dst[g]], 1);
}

__global__ __launch_bounds__(256) void k_scan_blk(const int* __restrict__ cnt,
                                                  int* __restrict__ rs,
                                                  int* __restrict__ bsum, int N) {
    __shared__ int s[256];
    int g = blockIdx.x * 256 + threadIdx.x;
    int v = (g < N) ? cnt[g] : 0;
    s[threadIdx.x] = v;
    __syncthreads();
    for (int off = 1; off < 256; off <<= 1) {
        int t = (threadIdx.x >= off) ? s[threadIdx.x - off] : 0;
        __syncthreads();
        s[threadIdx.x] += t;
        __syncthreads();
    }
    if (g < N) rs[g] = s[threadIdx.x] - v;
    if (threadIdx.x == 255) bsum[blockIdx.x] = s[255];
}

// parallel top scan, nb <= 512 (temporal: 480, spatial: 32)
__global__ __launch_bounds__(512) void k_scan_top(int* __restrict__ bsum, int nb) {
    __shared__ int s[512];
    int t = threadIdx.x;
    int v = (t < nb) ? bsum[t] : 0;
    s[t] = v;
    __syncthreads();
    for (int off = 1; off < 512; off <<= 1) {
        int x = (t >= off) ? s[t - off] : 0;
        __syncthreads();
        s[t] += x;
        __syncthreads();
    }
    if (t < nb) bsum[t] = s[t] - v;   // exclusive
}

__global__ __launch_bounds__(256) void k_scan_add(int* __restrict__ rs,
                                                  const int* __restrict__ bsum,
                                                  int* __restrict__ fill, int N) {
    int g = blockIdx.x * 256 + threadIdx.x;
    if (g < N) {
        int v = rs[g] + bsum[blockIdx.x];
        rs[g] = v;
        fill[g] = v;
    }
}

__global__ __launch_bounds__(256) void k_scatter(const int* __restrict__ src,
                                                 const int* __restrict__ dst,
                                                 int* __restrict__ fill,
                                                 int* __restrict__ csr, int E) {
    int g = blockIdx.x * 256 + threadIdx.x;
    if (g < E) {
        int p = atomicAdd(&fill[dst[g]], 1);
        csr[p] = src[g];
    }
}

// ---------------------------------------------------------------------------
// CSR aggregation, H=128, fused epilogue: Hout = relu(mean_agg(Y) + Z), bf16 split out
// ---------------------------------------------------------------------------
__global__ __launch_bounds__(256) void k_agg128(const int* __restrict__ rs,
                                                const int* __restrict__ cnt,
                                                const int* __restrict__ csr,
                                                const float* __restrict__ Y,
                                                const float* __restrict__ Z,
                                                ushort_t* __restrict__ Hh,
                                                ushort_t* __restrict__ Hl, int N) {
    int wid = (blockIdx.x * 256 + threadIdx.x) >> 6;
    int lane = threadIdx.x & 63;
    if (wid >= N) return;
    int s0 = rs[wid], c = cnt[wid];
    float2 acc = make_float2(0.f, 0.f);
    int j = 0;
    for (; j + 1 < c; j += 2) {
        int sa = csr[s0 + j], sb = csr[s0 + j + 1];
        float2 va = *reinterpret_cast<const float2*>(&Y[(size_t)sa * 128 + lane * 2]);
        float2 vb = *reinterpret_cast<const float2*>(&Y[(size_t)sb * 128 + lane * 2]);
        acc.x += va.x + vb.x; acc.y += va.y + vb.y;
    }
    if (j < c) {
        int sa = csr[s0 + j];
        float2 va = *reinterpret_cast<const float2*>(&Y[(size_t)sa * 128 + lane * 2]);
        acc.x += va.x; acc.y += va.y;
    }
    float rc = 1.f / fmaxf((float)c, 1.f);
    size_t idx = (size_t)wid * 128 + lane * 2;
    float2 z = *reinterpret_cast<const float2*>(&Z[idx]);
    float ox = fmaxf(acc.x * rc + z.x, 0.f);
    float oy = fmaxf(acc.y * rc + z.y, 0.f);
    ushort_t h, l;
    split_bf16(ox, h, l); Hh[idx] = h;     Hl[idx] = l;
    split_bf16(oy, h, l); Hh[idx + 1] = h; Hl[idx + 1] = l;
}

// ---------------------------------------------------------------------------
// CSR aggregation, H=64, fused epilogue: emb = l2norm(mean_agg(Y) + Z)
// ---------------------------------------------------------------------------
__global__ __launch_bounds__(256) void k_agg64n(const int* __restrict__ rs,
                                                const int* __restrict__ cnt,
                                                const int* __restrict__ csr,
                                                const float* __restrict__ Y,
                                                const float* __restrict__ Z,
                                                float* __restrict__ emb, int N) {
    int wid = (blockIdx.x * 256 + threadIdx.x) >> 6;
    int lane = threadIdx.x & 63;
    if (wid >= N) return;
    int s0 = rs[wid], c = cnt[wid];
    float acc = 0.f;
    int j = 0;
    for (; j + 1 < c; j += 2) {
        int sa = csr[s0 + j], sb = csr[s0 + j + 1];
        acc += Y[(size_t)sa * 64 + lane] + Y[(size_t)sb * 64 + lane];
    }
    if (j < c) acc += Y[(size_t)csr[s0 + j] * 64 + lane];
    float rc = 1.f / fmaxf((float)c, 1.f);
    size_t idx = (size_t)wid * 64 + lane;
    float v = acc * rc + Z[idx];
    float ss = v * v;
#pragma unroll
    for (int m = 32; m; m >>= 1) ss += __shfl_xor(ss, m, 64);
    float inv = 1.f / fmaxf(sqrtf(ss), 1e-12f);
    emb[idx] = v * inv;
}

// ---------------------------------------------------------------------------
// fp32 GEMM (projection heads): C[N,M] = A[N,K] @ W[K,M] (+bias) (optional relu)
// ---------------------------------------------------------------------------
#define BM 64
#define BN 64
#define BK 16
__global__ __launch_bounds__(256) void k_gemm(const float* __restrict__ A,
                                              const float* __restrict__ W,
                                              const float* __restrict__ bias,
                                              float* __restrict__ Co,
                                              int N, int K, int M, int relu) {
    __shared__ float As[BK][BM];
    __shared__ float Ws[BK][BN];
    int t = threadIdx.x;
    int row0 = blockIdx.x * BM;
    int col0 = blockIdx.y * BN;
    int lr = t >> 2;
    int lk = (t & 3) * 4;
    int wk = t >> 4;
    int wc = (t & 15) * 4;
    int ty = t >> 4;
    int tx = t & 15;
    float acc[4][4] = {};
    for (int k0 = 0; k0 < K; k0 += BK) {
        float4 av = *reinterpret_cast<const float4*>(&A[(size_t)(row0 + lr) * K + k0 + lk]);
        float4 wv = *reinterpret_cast<const float4*>(&W[(size_t)(k0 + wk) * M + col0 + wc]);
        __syncthreads();
        As[lk + 0][lr] = av.x; As[lk + 1][lr] = av.y;
        As[lk + 2][lr] = av.z; As[lk + 3][lr] = av.w;
        *reinterpret_cast<float4*>(&Ws[wk][wc]) = wv;
        __syncthreads();
#pragma unroll
        for (int kk = 0; kk < BK; ++kk) {
            float4 a  = *reinterpret_cast<const float4*>(&As[kk][ty * 4]);
            float4 w4 = *reinterpret_cast<const float4*>(&Ws[kk][tx * 4]);
            acc[0][0] += a.x * w4.x; acc[0][1] += a.x * w4.y; acc[0][2] += a.x * w4.z; acc[0][3] += a.x * w4.w;
            acc[1][0] += a.y * w4.x; acc[1][1] += a.y * w4.y; acc[1][2] += a.y * w4.z; acc[1][3] += a.y * w4.w;
            acc[2][0] += a.z * w4.x; acc[2][1] += a.z * w4.y; acc[2][2] += a.z * w4.z; acc[2][3] += a.z * w4.w;
            acc[3][0] += a.w * w4.x; acc[3][1] += a.w * w4.y; acc[3][2] += a.w * w4.z; acc[3][3] += a.w * w4.w;
        }
    }
    int cbase = col0 + tx * 4;
    float4 bv = make_float4(0.f, 0.f, 0.f, 0.f);
    if (bias) bv = *reinterpret_cast<const float4*>(&bias[cbase]);
#pragma unroll
    for (int i = 0; i < 4; ++i) {
        int r = row0 + ty * 4 + i;
        float4 o;
        o.x = acc[i][0] + bv.x; o.y = acc[i][1] + bv.y;
        o.z = acc[i][2] + bv.z; o.w = acc[i][3] + bv.w;
        if (relu) {
            o.x = fmaxf(o.x, 0.f); o.y = fmaxf(o.y, 0.f);
            o.z = fmaxf(o.z, 0.f); o.w = fmaxf(o.w, 0.f);
        }
        *reinterpret_cast<float4*>(&Co[(size_t)r * M + cbase]) = o;
    }
}

// ---------------------------------------------------------------------------
__global__ __launch_bounds__(256) void k_l2n128(const float* __restrict__ in,
                                                float* __restrict__ out, int N) {
    int wid = (blockIdx.x * 256 + threadIdx.x) >> 6;
    int lane = threadIdx.x & 63;
    if (wid >= N) return;
    size_t idx = (size_t)wid * 128 + lane * 2;
    float2 v = *reinterpret_cast<const float2*>(&in[idx]);
    float ss = v.x * v.x + v.y * v.y;
#pragma unroll
    for (int m = 32; m; m >>= 1) ss += __shfl_xor(ss, m, 64);
    float inv = 1.f / fmaxf(sqrtf(ss), 1e-12f);
    float2 o; o.x = v.x * inv; o.y = v.y * inv;
    *reinterpret_cast<float2*>(&out[idx]) = o;
}

__global__ __launch_bounds__(256) void k_tmean(const float* __restrict__ emb,
                                               float* __restrict__ out) {
    int gid = blockIdx.x * 256 + threadIdx.x;
    if (gid >= B_ * OUT_) return;
    int b = gid >> 6;
    int o = gid & 63;
    float s = 0.f;
#pragma unroll
    for (int w = 0; w < NW_; ++w) s += emb[((size_t)(b * NW_ + w)) * OUT_ + o];
    out[gid] = s * (1.f / NW_);
}

// ---------------------------------------------------------------------------
extern "C" void kernel_launch(void* const* d_in, const int* in_sizes, int n_in,
                              void* d_out, int out_size, void* d_ws, size_t ws_size,
                              hipStream_t stream) {
    const float* x      = (const float*)d_in[0];
    const int*   s_ei   = (const int*)d_in[1];
    const int*   t_ei   = (const int*)d_in[2];
    const float* s_l1_W  = (const float*)d_in[3];
    const float* s_l1_b  = (const float*)d_in[4];
    const float* s_l1_Wr = (const float*)d_in[5];
    const float* s_l2_W  = (const float*)d_in[6];
    const float* s_l2_b  = (const float*)d_in[7];
    const float* s_l2_Wr = (const float*)d_in[8];
    const float* s_p1_W  = (const float*)d_in[9];
    const float* s_p1_b  = (const float*)d_in[10];
    const float* s_p2_W  = (const float*)d_in[11];
    const float* s_p2_b  = (const float*)d_in[12];
    const float* t_l1_W  = (const float*)d_in[13];
    const float* t_l1_b  = (const float*)d_in[14];
    const float* t_l1_Wr = (const float*)d_in[15];
    const float* t_l2_W  = (const float*)d_in[16];
    const float* t_l2_b  = (const float*)d_in[17];
    const float* t_l2_Wr = (const float*)d_in[18];
    const float* t_p1_W  = (const float*)d_in[19];
    const float* t_p1_b  = (const float*)d_in[20];
    const float* t_p2_W  = (const float*)d_in[21];
    const float* t_p2_b  = (const float*)d_in[22];

    const int* s_src = s_ei, *s_dst = s_ei + E_S_;
    const int* t_src = t_ei, *t_dst = t_ei + E_T_;

    float* ws   = (float*)d_ws;
    float* dout = (float*)d_out;

    // ---- workspace (float units), no aliasing; ws is ~2.68 GB ----
    size_t o = 0;
    auto alloc = [&](size_t n) { float* r = ws + o; o += n; return r; };
    ushort_t* red_h  = (ushort_t*)alloc(15728640);
    ushort_t* red_l  = (ushort_t*)alloc(15728640);
    ushort_t* node_h = (ushort_t*)alloc(1048576);
    ushort_t* node_l = (ushort_t*)alloc(1048576);
    float* sY  = alloc(1048576);
    float* sZ  = alloc(1048576);
    ushort_t* sHh = (ushort_t*)alloc(524288);
    ushort_t* sHl = (ushort_t*)alloc(524288);
    float* s2Y = alloc(524288);
    float* s2Z = alloc(524288);
    float* sE  = alloc(524288);
    float* sP  = alloc(1048576);
    float* sT  = alloc(1048576);
    float* tY  = alloc(15728640);
    float* tZ  = alloc(15728640);
    ushort_t* tHh = (ushort_t*)alloc(7864320);
    ushort_t* tHl = (ushort_t*)alloc(7864320);
    float* t2Y = alloc(7864320);
    float* t2Z = alloc(7864320);
    float* tE  = alloc(7864320);
    float* tM  = alloc(524288);
    float* tP  = alloc(1048576);
    float* tT  = alloc(1048576);
    // converted-weight blob (shorts): per segment [hi | lo], transposed [M][K]
    ushort_t* wblob = (ushort_t*)alloc(163840);   // 327680 shorts
    ushort_t* swl1h = wblob + 0;      ushort_t* swl1l = wblob + 32768;
    ushort_t* swr1h = wblob + 65536;  ushort_t* swr1l = wblob + 98304;
    ushort_t* swl2h = wblob + 131072; ushort_t* swl2l = wblob + 139264;
    ushort_t* swr2h = wblob + 147456; ushort_t* swr2l = wblob + 155648;
    ushort_t* twl1h = wblob + 163840; ushort_t* twl1l = wblob + 196608;
    ushort_t* twr1h = wblob + 229376; ushort_t* twr1l = wblob + 262144;
    ushort_t* twl2h = wblob + 294912; ushort_t* twl2l = wblob + 303104;
    ushort_t* twr2h = wblob + 311296; ushort_t* twr2l = wblob + 319488;
    int* s_cnt  = (int*)alloc(8192);
    int* s_rs   = (int*)alloc(8192);
    int* s_fill = (int*)alloc(8192);
    int* s_csr  = (int*)alloc(262144);
    int* t_cnt  = (int*)alloc(122880);
    int* t_rs   = (int*)alloc(122880);
    int* t_fill = (int*)alloc(122880);
    int* t_csr  = (int*)alloc(983040);
    int* bsum   = (int*)alloc(512);

    // ---- K1 + weight conversion ----
    k_reduce_x<<<(B_ * C_) / 256, 256, 0, stream>>>(x, node_h, node_l, red_h, red_l);
    k_conv_all<<<640, 256, 0, stream>>>(s_l1_W, s_l1_Wr, s_l2_W, s_l2_Wr,
                                        t_l1_W, t_l1_Wr, t_l2_W, t_l2_Wr, wblob);

    // ---- spatial CSR ----
    hipMemsetAsync(s_cnt, 0, (size_t)B_ * 4, stream);
    k_cnt<<<E_S_ / 256, 256, 0, stream>>>(s_dst, s_cnt, E_S_);
    k_scan_blk<<<B_ / 256, 256, 0, stream>>>(s_cnt, s_rs, bsum, B_);
    k_scan_top<<<1, 512, 0, stream>>>(bsum, B_ / 256);
    k_scan_add<<<B_ / 256, 256, 0, stream>>>(s_rs, bsum, s_fill, B_);
    k_scatter<<<E_S_ / 256, 256, 0, stream>>>(s_src, s_dst, s_fill, s_csr, E_S_);

    // ---- spatial encoder ----
    k_mfma_gemm<256, 4><<<B_ / 128, 256, 0, stream>>>(node_h, node_l, swl1h, swl1l, nullptr, sY);
    k_mfma_gemm<256, 4><<<B_ / 128, 256, 0, stream>>>(node_h, node_l, swr1h, swr1l, s_l1_b, sZ);
    k_agg128<<<B_ / 4, 256, 0, stream>>>(s_rs, s_cnt, s_csr, sY, sZ, sHh, sHl, B_);
    k_mfma_gemm<128, 2><<<B_ / 128, 256, 0, stream>>>(sHh, sHl, swl2h, swl2l, nullptr, s2Y);
    k_mfma_gemm<128, 2><<<B_ / 128, 256, 0, stream>>>(sHh, sHl, swr2h, swr2l, s_l2_b, s2Z);
    k_agg64n<<<B_ / 4, 256, 0, stream>>>(s_rs, s_cnt, s_csr, s2Y, s2Z, sE, B_);
    k_gemm<<<dim3(B_ / 64, FD_ / 64), 256, 0, stream>>>(sE, s_p1_W, s_p1_b, sP, B_, OUT_, FD_, 1);
    k_gemm<<<dim3(B_ / 64, FD_ / 64), 256, 0, stream>>>(sP, s_p2_W, s_p2_b, sT, B_, FD_, FD_, 0);
    k_l2n128<<<B_ / 4, 256, 0, stream>>>(sT, dout, B_);

    // ---- temporal CSR ----
    hipMemsetAsync(t_cnt, 0, (size_t)NT_ * 4, stream);
    k_cnt<<<E_T_ / 256, 256, 0, stream>>>(t_dst, t_cnt, E_T_);
    k_scan_blk<<<NT_ / 256, 256, 0, stream>>>(t_cnt, t_rs, bsum, NT_);
    k_scan_top<<<1, 512, 0, stream>>>(bsum, NT_ / 256);
    k_scan_add<<<NT_ / 256, 256, 0, stream>>>(t_rs, bsum, t_fill, NT_);
    k_scatter<<<E_T_ / 256, 256, 0, stream>>>(t_src, t_dst, t_fill, t_csr, E_T_);

    // ---- temporal encoder ----
    k_mfma_gemm<256, 4><<<NT_ / 128, 256, 0, stream>>>(red_h, red_l, twl1h, twl1l, nullptr, tY);
    k_mfma_gemm<256, 4><<<NT_ / 128, 256, 0, stream>>>(red_h, red_l, twr1h, twr1l, t_l1_b, tZ);
    k_agg128<<<NT_ / 4, 256, 0, stream>>>(t_rs, t_cnt, t_csr, tY, tZ, tHh, tHl, NT_);
    k_mfma_gemm<128, 2><<<NT_ / 128, 256, 0, stream>>>(tHh, tHl, twl2h, twl2l, nullptr, t2Y);
    k_mfma_gemm<128, 2><<<NT_ / 128, 256, 0, stream>>>(tHh, tHl, twr2h, twr2l, t_l2_b, t2Z);
    k_agg64n<<<NT_ / 4, 256, 0, stream>>>(t_rs, t_cnt, t_csr, t2Y, t2Z, tE, NT_);
    k_tmean<<<(B_ * OUT_) / 256, 256, 0, stream>>>(tE, tM);
    k_gemm<<<dim3(B_ / 64, FD_ / 64), 256, 0, stream>>>(tM, t_p1_W, t_p1_b, tP, B_, OUT_, FD_, 1);
    k_gemm<<<dim3(B_ / 64, FD_ / 64), 256, 0, stream>>>(tP, t_p2_W, t_p2_b, tT, B_, FD_, FD_, 0);
    k_l2n128<<<B_ / 4, 256, 0, stream>>>(tT, dout + (size_t)B_ * FD_, B_);
}